// Round 13
// baseline (726.752 us; speedup 1.0000x reference)
//
#include <hip/hip_runtime.h>

typedef __bf16 bf16;
typedef __bf16 bf16x4_t __attribute__((ext_vector_type(4)));
typedef __bf16 bf16x8_t __attribute__((ext_vector_type(8)));
typedef float f32x4 __attribute__((ext_vector_type(4)));

#define DEVI __device__ __forceinline__

// ---------------- problem constants ----------------
#define N_B   16
#define N_C   768
#define N_S   729
#define N_TOK 11664          // 16*729
#define TOKP  11776          // 92*128 padded token rows
#define N_H   8
#define N_D   96
#define N_HID 3072
#define MOE_TILES 94         // max 128-row tiles after per-expert 128-padding
#define GATE_BLOCKS 183      // 183 blocks * 4 waves * 16 toks = 11712 >= N_TOK

// ---------------- workspace layout (bytes) ----------------
#define OFF_WQKVH 0ull                  // bf16 [2304][768]
#define OFF_WQKVL 3538944ull
#define OFF_WOUTH 7077888ull            // bf16 [768][768]
#define OFF_WOUTL 8257536ull
#define OFF_W1T   9437184ull            // bf16 [3][3072][768]
#define OFF_W2T   23592960ull           // bf16 [3][768][3072]
#define OFF_XTOK  37748736ull           // f32 [TOKP][768]   -> later MOE f32
#define OFF_R3    73924608ull           // TOK hi/lo -> VT hi/lo -> T2H
#define OFF_TOKH  OFF_R3
#define OFF_TOKL  (OFF_R3 + 18087936ull)
#define OFF_VTH   OFF_R3                // bf16 [128][96][736]
#define OFF_VTL   (OFF_R3 + 18087936ull)
#define OFF_T2H   OFF_R3                // bf16 [TOKP][768]
#define OFF_QKH   110100480ull          // bf16 [TOKP][1536] -> HMID (compacted, 12032 rows)
#define OFF_QKL   146276352ull
#define OFF_VPH   182452224ull          // bf16 [TOKP][768]  -> (dead after attn; HMID tail)
#define OFF_VPL   200540160ull
#define OFF_CTXH  OFF_VPH
#define OFF_CTXL  OFF_VPL
#define OFF_HMID  OFF_QKH               // bf16 [12032][3072] = 73.9 MB (QKH..+CTXH head, all dead)
#define OFF_X2    218628096ull          // f32 [TOKP][768]
#define OFF_STATS 254803968ull          // double [16][2]
#define OFF_DENOM (OFF_STATS + 256ull)  // f32 [729][3]
#define OFF_SEL   (OFF_STATS + 16384ull)
#define OFF_PVAL  (OFF_SEL + 65536ull)
#define OFF_GSV   (OFF_PVAL + 65536ull) // f32 [N_TOK]
#define OFF_PERM  (OFF_GSV + 65536ull)  // int [94*128]
#define OFF_CNT   (OFF_PERM + 65536ull) // int cnt[4], poff[4], cur[4]

// ---------------- helpers ----------------
DEVI f32x4 mfma16(bf16x8_t a, bf16x8_t b, f32x4 c) {
  return __builtin_amdgcn_mfma_f32_16x16x32_bf16(a, b, c, 0, 0, 0);
}
// Native RNE conversion (hw cvt; bit-identical to the old RNE bit hack).
DEVI bf16 f2bf(float f) { return (bf16)f; }
DEVI float bf2f(bf16 h) { return (float)h; }
#define GLDS(gp, lp) __builtin_amdgcn_global_load_lds( \
    (__attribute__((address_space(1))) void*)(gp),     \
    (__attribute__((address_space(3))) void*)(lp), 16, 0, 0)

// XCD-aware bijective block remap (T1, m204 uneven-chunk form).
DEVI void xcd_swz(int& bx, int& by) {
  int gx = gridDim.x;
  int nwg = gx * gridDim.y;
  int lin = blockIdx.x + gx * blockIdx.y;
  int xcd = lin & 7, j = lin >> 3;
  int q = nwg >> 3, r = nwg & 7;
  int base = (xcd < r) ? xcd * (q + 1) : r * (q + 1) + (xcd - r) * q;
  int g = base + j;
  by = g / gx;
  bx = g - by * gx;
}

// ---------------- weight transpose + bf16 hi/lo ----------------
template<bool SPLIT>
__global__ void kxpose(const float* __restrict__ in, bf16* __restrict__ oh,
                       bf16* __restrict__ ol, int R, int Cc) {
  __shared__ float T[32][33];
  int c0 = blockIdx.x * 32, r0 = blockIdx.y * 32;
  int tx = threadIdx.x, ty = threadIdx.y;
#pragma unroll
  for (int i = 0; i < 4; i++)
    T[ty + i * 8][tx] = in[(size_t)(r0 + ty + i * 8) * Cc + c0 + tx];
  __syncthreads();
#pragma unroll
  for (int i = 0; i < 4; i++) {
    float v = T[tx][ty + i * 8];
    size_t o = (size_t)(c0 + ty + i * 8) * R + r0 + tx;
    bf16 hh = f2bf(v);
    oh[o] = hh;
    if constexpr (SPLIT) ol[o] = f2bf(v - bf2f(hh));
  }
}

// ---------------- LayerNorm ----------------
__global__ __launch_bounds__(256) void ln_stats(const float* __restrict__ x,
                                                double* __restrict__ stats) {
  int b = blockIdx.x >> 7, ch = blockIdx.x & 127;
  const float* xb = x + (size_t)b * 559872;
  int start = ch * 4374;
  float s = 0.f, ss = 0.f;
  for (int i = start + threadIdx.x; i < start + 4374; i += 256) {
    float v = xb[i];
    s += v; ss += v * v;
  }
#pragma unroll
  for (int o = 32; o > 0; o >>= 1) { s += __shfl_down(s, o); ss += __shfl_down(ss, o); }
  __shared__ float rs[4], rss[4];
  int w = threadIdx.x >> 6;
  if ((threadIdx.x & 63) == 0) { rs[w] = s; rss[w] = ss; }
  __syncthreads();
  if (threadIdx.x == 0) {
    atomicAdd(&stats[b * 2 + 0], (double)(rs[0] + rs[1] + rs[2] + rs[3]));
    atomicAdd(&stats[b * 2 + 1], (double)(rss[0] + rss[1] + rss[2] + rss[3]));
  }
}

__global__ void ln_apply(const float* __restrict__ x, const float* __restrict__ g,
                         const float* __restrict__ be, const double* __restrict__ stats,
                         float* __restrict__ xtok, bf16* __restrict__ th, bf16* __restrict__ tl) {
  __shared__ float TN[32][33], TX[32][33];
  int b = blockIdx.z, c0 = blockIdx.y * 32, s0 = blockIdx.x * 32;
  double mu = stats[b * 2] * (1.0 / 559872.0);
  double var = stats[b * 2 + 1] * (1.0 / 559872.0) - mu * mu;
  float rstd = (float)(1.0 / sqrt(var + 1e-5));
  float muf = (float)mu;
  int tx = threadIdx.x, ty = threadIdx.y;
  size_t bo = (size_t)b * 559872;
#pragma unroll
  for (int i = 0; i < 4; i++) {
    int c = c0 + ty + i * 8, s = s0 + tx;
    float v = 0.f, xn = 0.f;
    if (s < N_S) {
      v = x[bo + (size_t)c * 729 + s];
      xn = (v - muf) * rstd * g[(size_t)c * 729 + s] + be[(size_t)c * 729 + s];
    }
    TX[ty + i * 8][tx] = v;
    TN[ty + i * 8][tx] = xn;
  }
  __syncthreads();
#pragma unroll
  for (int i = 0; i < 4; i++) {
    int s = s0 + ty + i * 8;
    if (s < N_S) {
      size_t tok = (size_t)b * 729 + s;
      int c = c0 + tx;
      float xv = TX[tx][ty + i * 8];
      float xn = TN[tx][ty + i * 8];
      xtok[tok * 768 + c] = xv;
      bf16 hh = f2bf(xn);
      th[tok * 768 + c] = hh;
      tl[tok * 768 + c] = f2bf(xn - bf2f(hh));
    }
  }
}

// ---------------- generic bf16(-split) MFMA GEMM, 128x128 tile, BK=64 ----------------
// R8-proven structure: all four operands staged via global_load_lds (64KB LDS,
// 2 blocks/CU). EPI_QKV: one dispatch over all 2304 WQKV cols.
enum { EPI_QKV = 0, EPI_ATTNOUT = 1 };

template<int EPI, bool SPLIT>
__global__ __launch_bounds__(256, 2)
void gemm_k(const bf16* __restrict__ Ah, const bf16* __restrict__ Al,
            const bf16* __restrict__ Bh, const bf16* __restrict__ Bl,
            int M, int N, int K,
            bf16* __restrict__ o0, bf16* __restrict__ o1,
            bf16* __restrict__ o2, bf16* __restrict__ o3,
            float* __restrict__ of, const float* __restrict__ fa) {
  __shared__ __align__(16) bf16 Ash[8192], Bsh[8192];
  __shared__ __align__(16) bf16 Asl[SPLIT ? 8192 : 8], Bsl[SPLIT ? 8192 : 8];
  const int t = threadIdx.x;
  const int lane = t & 63, w = t >> 6;
  const int wr = (w >> 1) << 6, wc = (w & 1) << 6;
  const int lr = lane & 15, lg = lane >> 4;
  int sbx, sby; xcd_swz(sbx, sby);
  const size_t arow = (size_t)sby * 128;
  const size_t brow = (size_t)sbx * 128;
  const int sr = t >> 3;                        // staging row within 32-row group
  const int sg = ((t & 7) ^ (sr & 7)) << 3;     // pre-swizzled col group (elements)
  const bf16* pA = Ah + (arow + sr) * (size_t)K + sg;
  const bf16* pB = Bh + (brow + sr) * (size_t)K + sg;
  const bf16 *pAl = nullptr, *pBl = nullptr;
  if constexpr (SPLIT) {
    pAl = Al + (arow + sr) * (size_t)K + sg;
    pBl = Bl + (brow + sr) * (size_t)K + sg;
  }
  const size_t rstep = (size_t)K << 5;          // 32 rows
  f32x4 acc[4][4] = {};
  for (int k0 = 0; k0 < K; k0 += 64) {
    __syncthreads();
#pragma unroll
    for (int c = 0; c < 4; c++) {
      GLDS(pA + c * rstep + k0, &Ash[c * 2048 + t * 8]);
      GLDS(pB + c * rstep + k0, &Bsh[c * 2048 + t * 8]);
      if constexpr (SPLIT) {
        GLDS(pAl + c * rstep + k0, &Asl[c * 2048 + t * 8]);
        GLDS(pBl + c * rstep + k0, &Bsl[c * 2048 + t * 8]);
      }
    }
    asm volatile("s_waitcnt vmcnt(0)" ::: "memory");
    __syncthreads();
#pragma unroll
    for (int kk = 0; kk < 2; kk++) {
      bf16x8_t af[4], bq[4], afl[4], bql[4];
#pragma unroll
      for (int m = 0; m < 4; m++) {
        int row = wr + m * 16 + lr;
        int off = row * 64 + ((((kk << 2) | lg) ^ (row & 7)) << 3);
        af[m] = *(const bf16x8_t*)&Ash[off];
        if constexpr (SPLIT) afl[m] = *(const bf16x8_t*)&Asl[off];
      }
#pragma unroll
      for (int n = 0; n < 4; n++) {
        int row = wc + n * 16 + lr;
        int off = row * 64 + ((((kk << 2) | lg) ^ (row & 7)) << 3);
        bq[n] = *(const bf16x8_t*)&Bsh[off];
        if constexpr (SPLIT) bql[n] = *(const bf16x8_t*)&Bsl[off];
      }
#pragma unroll
      for (int m = 0; m < 4; m++)
#pragma unroll
        for (int n = 0; n < 4; n++) {
          acc[m][n] = mfma16(af[m], bq[n], acc[m][n]);
          if constexpr (SPLIT) {
            acc[m][n] = mfma16(af[m], bql[n], acc[m][n]);
            acc[m][n] = mfma16(afl[m], bq[n], acc[m][n]);
          }
        }
    }
  }
#pragma unroll
  for (int m = 0; m < 4; m++) {
#pragma unroll
    for (int r = 0; r < 4; r++) {
      int gr = (int)arow + wr + m * 16 + lg * 4 + r;
      if (gr >= M) continue;
#pragma unroll
      for (int n = 0; n < 4; n++) {
        int gc = (int)brow + wc + n * 16 + lr;
        float v = acc[m][n][r];
        if constexpr (EPI == EPI_QKV) {
          bf16 hh = f2bf(v);
          bf16 ll = f2bf(v - bf2f(hh));
          if (gc < 1536) {
            size_t oidx = (size_t)gr * 1536 + gc;
            o0[oidx] = hh;
            o1[oidx] = ll;
          } else {
            size_t oidx = (size_t)gr * 768 + (gc - 1536);
            o2[oidx] = hh;
            o3[oidx] = ll;
          }
        } else {  // EPI_ATTNOUT
          float x2v = v + fa[(size_t)gr * 768 + gc];
          of[(size_t)gr * 768 + gc] = x2v;
          o0[(size_t)gr * 768 + gc] = f2bf(x2v);
        }
      }
    }
  }
}

// ---------------- grouped MoE GEMM1: 2-phase dbuf pipeline (T3-minimum) ----------------
// Stage(next) issued BEFORE compute(cur); the end-of-iter __syncthreads drains
// the in-flight stage loads AFTER compute hid their latency. One barrier per
// K-step (was two) and staging fully overlapped. LDS 64KB -> 2 blocks/CU.
__global__ __launch_bounds__(256, 2)
void gemm_moe1(const bf16* __restrict__ Ah, const bf16* __restrict__ W1T,
               const float* __restrict__ b1, const int* __restrict__ perm,
               const int* __restrict__ poff, bf16* __restrict__ hmid) {
  int sbx, sby; xcd_swz(sbx, sby);
  const int arow = sby * 128;
  if (arow >= poff[3]) return;
  const int e = (arow >= poff[1]) + (arow >= poff[2]);
  const bf16* Bh = W1T + (size_t)e * 3072 * 768;
  const float* bias = b1 + e * 3072;
  __shared__ __align__(16) bf16 Ash[2][8192], Bsh[2][8192];
  const int t = threadIdx.x;
  const int lane = t & 63, w = t >> 6;
  const int wr = (w >> 1) << 6, wc = (w & 1) << 6;
  const int lr = lane & 15, lg = lane >> 4;
  const size_t brow = (size_t)sbx * 128;
  const int sr = t >> 3;
  const int sg = ((t & 7) ^ (sr & 7)) << 3;
  int ip[4];
#pragma unroll
  for (int c = 0; c < 4; c++) {
    int ii = perm[arow + c * 32 + sr];
    ip[c] = (ii < 0) ? 0 : ii;
  }
  const bf16* pB = Bh + (brow + sr) * 768 + sg;
  const size_t rstep = 768ull << 5;
  auto stage = [&](int buf, int k0) {
#pragma unroll
    for (int c = 0; c < 4; c++) {
      GLDS(Ah + (size_t)ip[c] * 768 + sg + k0, &Ash[buf][c * 2048 + t * 8]);
      GLDS(pB + c * rstep + k0, &Bsh[buf][c * 2048 + t * 8]);
    }
  };
  f32x4 acc[4][4] = {};
  stage(0, 0);
  asm volatile("s_waitcnt vmcnt(0)" ::: "memory");
  __syncthreads();
  int cur = 0;
  for (int k0 = 0; k0 < 768; k0 += 64) {
    if (k0 + 64 < 768) stage(cur ^ 1, k0 + 64);
#pragma unroll
    for (int kk = 0; kk < 2; kk++) {
      bf16x8_t af[4], bq[4];
#pragma unroll
      for (int m = 0; m < 4; m++) {
        int row = wr + m * 16 + lr;
        af[m] = *(const bf16x8_t*)&Ash[cur][row * 64 + ((((kk << 2) | lg) ^ (row & 7)) << 3)];
      }
#pragma unroll
      for (int n = 0; n < 4; n++) {
        int row = wc + n * 16 + lr;
        bq[n] = *(const bf16x8_t*)&Bsh[cur][row * 64 + ((((kk << 2) | lg) ^ (row & 7)) << 3)];
      }
#pragma unroll
      for (int m = 0; m < 4; m++)
#pragma unroll
        for (int n = 0; n < 4; n++)
          acc[m][n] = mfma16(af[m], bq[n], acc[m][n]);
    }
    __syncthreads();   // drains vmcnt (stage complete) + all waves done reading cur
    cur ^= 1;
  }
#pragma unroll
  for (int m = 0; m < 4; m++)
#pragma unroll
    for (int r = 0; r < 4; r++) {
      int gr = arow + wr + m * 16 + lg * 4 + r;
#pragma unroll
      for (int n = 0; n < 4; n++) {
        int gc = (int)brow + wc + n * 16 + lr;
        float z = acc[m][n][r] + bias[gc];
        float gl = 0.5f * z * (1.f + erff(z * 0.7071067811865476f));
        hmid[(size_t)gr * 3072 + gc] = f2bf(gl);
      }
    }
}

// ---------------- grouped MoE GEMM2: 2-phase dbuf pipeline (T3-minimum) ----------------
__global__ __launch_bounds__(256, 2)
void gemm_moe2(const bf16* __restrict__ hmid, const bf16* __restrict__ W2T,
               const float* __restrict__ b2, const int* __restrict__ perm,
               const int* __restrict__ poff, const float* __restrict__ gsv,
               float* __restrict__ moe) {
  int sbx, sby; xcd_swz(sbx, sby);
  const int arow = sby * 128;
  if (arow >= poff[3]) return;
  const int e = (arow >= poff[1]) + (arow >= poff[2]);
  const bf16* Bh = W2T + (size_t)e * 768 * 3072;
  const float* bias = b2 + e * 768;
  __shared__ __align__(16) bf16 Ash[2][8192], Bsh[2][8192];
  const int t = threadIdx.x;
  const int lane = t & 63, w = t >> 6;
  const int wr = (w >> 1) << 6, wc = (w & 1) << 6;
  const int lr = lane & 15, lg = lane >> 4;
  const size_t brow = (size_t)sbx * 128;
  const int sr = t >> 3;
  const int sg = ((t & 7) ^ (sr & 7)) << 3;
  const bf16* pA = hmid + (size_t)(arow + sr) * 3072 + sg;
  const bf16* pB = Bh + (brow + sr) * 3072 + sg;
  const size_t rstep = 3072ull << 5;
  auto stage = [&](int buf, int k0) {
#pragma unroll
    for (int c = 0; c < 4; c++) {
      GLDS(pA + c * rstep + k0, &Ash[buf][c * 2048 + t * 8]);
      GLDS(pB + c * rstep + k0, &Bsh[buf][c * 2048 + t * 8]);
    }
  };
  f32x4 acc[4][4] = {};
  stage(0, 0);
  asm volatile("s_waitcnt vmcnt(0)" ::: "memory");
  __syncthreads();
  int cur = 0;
  for (int k0 = 0; k0 < 3072; k0 += 64) {
    if (k0 + 64 < 3072) stage(cur ^ 1, k0 + 64);
#pragma unroll
    for (int kk = 0; kk < 2; kk++) {
      bf16x8_t af[4], bq[4];
#pragma unroll
      for (int m = 0; m < 4; m++) {
        int row = wr + m * 16 + lr;
        af[m] = *(const bf16x8_t*)&Ash[cur][row * 64 + ((((kk << 2) | lg) ^ (row & 7)) << 3)];
      }
#pragma unroll
      for (int n = 0; n < 4; n++) {
        int row = wc + n * 16 + lr;
        bq[n] = *(const bf16x8_t*)&Bsh[cur][row * 64 + ((((kk << 2) | lg) ^ (row & 7)) << 3)];
      }
#pragma unroll
      for (int m = 0; m < 4; m++)
#pragma unroll
        for (int n = 0; n < 4; n++)
          acc[m][n] = mfma16(af[m], bq[n], acc[m][n]);
    }
    __syncthreads();   // drains vmcnt (stage complete) + all waves done reading cur
    cur ^= 1;
  }
#pragma unroll
  for (int m = 0; m < 4; m++)
#pragma unroll
    for (int r = 0; r < 4; r++) {
      int gr = arow + wr + m * 16 + lg * 4 + r;
      int tok = perm[gr];
      if (tok < 0) continue;
      float gv = gsv[tok];
#pragma unroll
      for (int n = 0; n < 4; n++) {
        int gc = (int)brow + wc + n * 16 + lr;
        moe[(size_t)tok * 768 + gc] = (acc[m][n][r] + bias[gc]) * gv;
      }
    }
}

// ---------------- V repack: [tok][h*96+d] -> [bh][96][736] (zero pad s>=729) ----------------
__global__ __launch_bounds__(256) void repack_v(const bf16* __restrict__ vph,
    const bf16* __restrict__ vpl, bf16* __restrict__ vth, bf16* __restrict__ vtl) {
  __shared__ bf16 Lh[96][40], Ll[96][40];
  int t = threadIdx.x;
  int bh = blockIdx.y, b = bh >> 3, h = bh & 7;
  int s0 = blockIdx.x * 32;
  for (int v = t; v < 384; v += 256) {
    int e0 = v * 8;
    int r = e0 / 96;
    int c = e0 - r * 96;
    size_t src = ((size_t)b * 729 + s0 + r) * 768 + h * 96 + c;
    bf16x8_t xh = *(const bf16x8_t*)&vph[src];
    bf16x8_t xl = *(const bf16x8_t*)&vpl[src];
    bool ok = (s0 + r) < N_S;
#pragma unroll
    for (int j = 0; j < 8; j++) {
      Lh[c + j][r] = ok ? xh[j] : f2bf(0.f);
      Ll[c + j][r] = ok ? xl[j] : f2bf(0.f);
    }
  }
  __syncthreads();
  for (int vv = t; vv < 768; vv += 256) {
    int e0 = vv * 4;
    int d = e0 >> 5, sl = e0 & 31;
    bf16x4_t ohv, olv;
#pragma unroll
    for (int j = 0; j < 4; j++) { ohv[j] = Lh[d][sl + j]; olv[j] = Ll[d][sl + j]; }
    size_t dst = (size_t)bh * (96ull * 736ull) + (size_t)d * 736 + s0 + sl;
    *(bf16x4_t*)&vth[dst] = ohv;
    *(bf16x4_t*)&vtl[dst] = olv;
  }
}

// ---------------- fused attention (split bf16, online softmax) ----------------
// Proven R6 structure (256 thr, QBLK=64, LDS 48KB, 3 blocks/CU, 84 VGPR).
DEVI int pslot(int w, int s) { return ((s >> 9) << 11) + (w << 9) + (s & 511); }

__global__ __launch_bounds__(256, 3)
void attn(const bf16* __restrict__ qkh, const bf16* __restrict__ qkl,
          const bf16* __restrict__ vth, const bf16* __restrict__ vtl,
          bf16* __restrict__ ch, bf16* __restrict__ cl) {
  __shared__ bf16 Ksh[6144], Ksl[6144], Vsh[6144], Vsl[6144];
  const int t = threadIdx.x, lane = t & 63, w = t >> 6;
  const int lr = lane & 15, lg = lane >> 4;
  int sbx, sby; xcd_swz(sbx, sby);
  const int bh = sby, b = bh >> 3, h = bh & 7;
  const int q0 = sbx * 64;
  const size_t tokbase = (size_t)b * 729;
  const int qr = w * 16 + lr;
  const size_t qrow = (tokbase + q0 + qr) * 1536ull + (size_t)h * 96;
  bf16x8_t qh[3], ql[3];
#pragma unroll
  for (int ks = 0; ks < 3; ks++) {
    qh[ks] = *(const bf16x8_t*)&qkh[qrow + ks * 32 + lg * 8];
    ql[ks] = *(const bf16x8_t*)&qkl[qrow + ks * 32 + lg * 8];
  }

  auto loadK = [&](int kt) {
    const int kv0 = kt * 64;
#pragma unroll
    for (int chk = 0; chk < 3; chk++) {
      int kv = t >> 2, dg = t & 3;
      int sdg = dg ^ (kv & 3);
      size_t ksrc = (tokbase + kv0 + kv) * 1536ull + 768ull + (size_t)h * 96 + chk * 32 + (sdg << 3);
      int ldsoff = chk * 2048 + t * 8;
      GLDS(qkh + ksrc, &Ksh[ldsoff]);
      GLDS(qkl + ksrc, &Ksl[ldsoff]);
    }
  };
  auto loadV = [&](int kt) {
    const int kv0 = kt * 64;
#pragma unroll
    for (int chk = 0; chk < 3; chk++) {
      int ldsoff = chk * 2048 + t * 8;
      int d = ldsoff >> 6;
      int grp = (ldsoff >> 3) & 7;
      int sg = grp ^ (d & 7);
      size_t vsrc = (size_t)bh * (96ull * 736ull) + (size_t)d * 736 + kv0 + (sg << 3);
      GLDS(vth + vsrc, &Vsh[ldsoff]);
      GLDS(vtl + vsrc, &Vsl[ldsoff]);
    }
  };

  float mrow[4] = {-1e30f, -1e30f, -1e30f, -1e30f};
  float lpart[4] = {0.f, 0.f, 0.f, 0.f};   // per-lane partial denominators
  f32x4 octx[6] = {};

  // prologue: K[0] fully staged (Q loads drained together), then launch V[0]
  loadK(0);
  asm volatile("s_waitcnt vmcnt(0)" ::: "memory");
  __syncthreads();
  loadV(0);

  for (int kt = 0; kt < 12; kt++) {
    const int kv0 = kt * 64;
    // ---- QK^T from Ksh (V[kt] loads in flight underneath) ----
    f32x4 sc[4];
    __builtin_amdgcn_s_setprio(1);
#pragma unroll
    for (int cf = 0; cf < 4; cf++) {
      f32x4 a = {0.f, 0.f, 0.f, 0.f};
      int kvrow = cf * 16 + lr;
#pragma unroll
      for (int ks = 0; ks < 3; ks++) {
        int slot = ks * 2048 + kvrow * 32 + ((lg ^ (kvrow & 3)) << 3);
        bf16x8_t kh = *(const bf16x8_t*)&Ksh[slot];
        bf16x8_t kl = *(const bf16x8_t*)&Ksl[slot];
        a = mfma16(qh[ks], kh, a);
        a = mfma16(qh[ks], kl, a);
        a = mfma16(ql[ks], kh, a);
      }
      if (kv0 + kvrow >= N_S) { a[0] = -1e30f; a[1] = -1e30f; a[2] = -1e30f; a[3] = -1e30f; }
      sc[cf] = a;
    }
    __builtin_amdgcn_s_setprio(0);
    // ---- online softmax with defer-max (THR=8) ----
    float lmax[4];
#pragma unroll
    for (int r = 0; r < 4; r++)
      lmax[r] = fmaxf(fmaxf(sc[0][r], sc[1][r]), fmaxf(sc[2][r], sc[3][r]));
    bool ok = (lmax[0] <= mrow[0] + 8.f) && (lmax[1] <= mrow[1] + 8.f) &&
              (lmax[2] <= mrow[2] + 8.f) && (lmax[3] <= mrow[3] + 8.f);
    if (!__all(ok)) {
      float escv[4];
#pragma unroll
      for (int r = 0; r < 4; r++) {
        float a = lmax[r];
#pragma unroll
        for (int o = 1; o < 16; o <<= 1) a = fmaxf(a, __shfl_xor(a, o));
        float mn = fmaxf(mrow[r], a);
        escv[r] = __expf(mrow[r] - mn);
        mrow[r] = mn;
        lpart[r] *= escv[r];
      }
#pragma unroll
      for (int df = 0; df < 6; df++)
#pragma unroll
        for (int r = 0; r < 4; r++) octx[df][r] *= escv[r];
    }
#pragma unroll
    for (int cf = 0; cf < 4; cf++)
#pragma unroll
      for (int r = 0; r < 4; r++) {
        float p = __expf(sc[cf][r] - mrow[r]);
        sc[cf][r] = p;
        lpart[r] += p;
      }
    // drain own V[kt]; barrier => everyone done reading Ksh, V tile complete
    asm volatile("s_waitcnt vmcnt(0)" ::: "memory");
    __syncthreads();
    // ---- P into own slice of dead K tile (wave-private) ----
#pragma unroll
    for (int cf = 0; cf < 4; cf++)
#pragma unroll
      for (int r = 0; r < 4; r++) {
        int qloc = lg * 4 + r;
        int kvg = (cf << 1) | (lr >> 3);
        int xw = (qloc ^ (qloc >> 2)) & 7;
        int slot = qloc * 64 + (((kvg ^ xw) << 3) | (lr & 7));
        float p = sc[cf][r];
        bf16 hp = f2bf(p);
        int ps = pslot(w, slot);
        Ksh[ps] = hp;
        Ksl[ps] = f2bf(p - bf2f(hp));
      }
    asm volatile("s_waitcnt lgkmcnt(0)" ::: "memory");
    __builtin_amdgcn_sched_barrier(0);
    bf16x8_t pah[2], pal[2];
#pragma unroll
    for (int ks = 0; ks < 2; ks++) {
      int xr = (lr ^ (lr >> 2)) & 7;
      int slot = lr * 64 + ((((ks << 2) | lg) ^ xr) << 3);
      int ps = pslot(w, slot);
      pah[ks] = *(const bf16x8_t*)&Ksh[ps];
      pal[ks] = *(const bf16x8_t*)&Ksl[ps];
    }
    asm volatile("s_waitcnt lgkmcnt(0)" ::: "memory");
    __builtin_amdgcn_sched_barrier(0);
    // P fragments now in registers: safe to launch K[kt+1] over own K/P slice
    if (kt < 11) loadK(kt + 1);
    // ---- PV from Vsh (K[kt+1] loads in flight underneath) ----
    __builtin_amdgcn_s_setprio(1);
#pragma unroll
    for (int df = 0; df < 6; df++) {
      int dd = df * 16 + lr;
#pragma unroll
      for (int ks = 0; ks < 2; ks++) {
        int slot = dd * 64 + ((((ks << 2) | lg) ^ (dd & 7)) << 3);
        bf16x8_t vh = *(const bf16x8_t*)&Vsh[slot];
        bf16x8_t vl = *(const bf16x8_t*)&Vsl[slot];
        octx[df] = mfma16(pah[ks], vh, octx[df]);
        octx[df] = mfma16(pah[ks], vl, octx[df]);
        octx[df] = mfma16(pal[ks], vh, octx[df]);
      }
    }
    __builtin_amdgcn_s_setprio(0);
    if (kt < 11) {
      // drain own K[kt+1]; barrier => everyone done reading Vsh, K complete
      asm volatile("s_waitcnt vmcnt(0)" ::: "memory");
      __syncthreads();
      loadV(kt + 1);
    }
  }
  // epilogue: reduce per-lane partial denominators across the 16-lane row group
  float lrow[4];
#pragma unroll
  for (int r = 0; r < 4; r++) {
    float a = lpart[r];
#pragma unroll
    for (int o = 1; o < 16; o <<= 1) a += __shfl_xor(a, o);
    lrow[r] = a;
  }
#pragma unroll
  for (int r = 0; r < 4; r++) {
    int qloc = w * 16 + lg * 4 + r;
    if (q0 + qloc >= N_S) continue;
    size_t orow = (tokbase + q0 + qloc) * 768ull + (size_t)h * 96;
    float inv = 1.f / lrow[r];
#pragma unroll
    for (int df = 0; df < 6; df++) {
      float v = octx[df][r] * inv;
      bf16 hh = f2bf(v);
      ch[orow + df * 16 + lr] = hh;
      cl[orow + df * 16 + lr] = f2bf(v - bf2f(hh));
    }
  }
}

// ---------------- gate: fp64 logits, argmax, cross-batch denom, counts ----------------
__global__ __launch_bounds__(256) void gate_k(const float* __restrict__ x2,
    const float* __restrict__ wg, const float* __restrict__ bg,
    int* __restrict__ sel, float* __restrict__ pval, float* __restrict__ denom,
    int* __restrict__ cnt) {
  int lane = threadIdx.x & 63, w = threadIdx.x >> 6;
  float wv[12][3];
#pragma unroll
  for (int j = 0; j < 12; j++) {
    int c = lane + j * 64;
    const float* wgc = wg + c * 3;
    wv[j][0] = wgc[0]; wv[j][1] = wgc[1]; wv[j][2] = wgc[2];
  }
  float bg0 = bg[0], bg1 = bg[1], bg2 = bg[2];
  int cloc0 = 0, cloc1 = 0, cloc2 = 0;
  int base_tok = (blockIdx.x * 4 + w) * 16;
  for (int it = 0; it < 16; it++) {
    int tok = base_tok + it;
    if (tok >= N_TOK) break;   // wave-uniform
    const float* row = x2 + (size_t)tok * 768;
    double a0 = 0, a1 = 0, a2 = 0;
#pragma unroll
    for (int j = 0; j < 12; j++) {
      float xv = row[lane + j * 64];
      a0 += (double)(xv * wv[j][0]);
      a1 += (double)(xv * wv[j][1]);
      a2 += (double)(xv * wv[j][2]);
    }
#pragma unroll
    for (int o = 32; o > 0; o >>= 1) {
      a0 += __shfl_down(a0, o);
      a1 += __shfl_down(a1, o);
      a2 += __shfl_down(a2, o);
    }
    if (lane == 0) {
      float g0 = (float)a0 + bg0, g1 = (float)a1 + bg1, g2 = (float)a2 + bg2;
      float mx = fmaxf(g0, fmaxf(g1, g2));
      float e0 = __expf(g0 - mx), e1 = __expf(g1 - mx), e2 = __expf(g2 - mx);
      float inv = 1.f / (e0 + e1 + e2);
      int am = 0; float pm = e0;
      if (e1 > pm) { pm = e1; am = 1; }
      if (e2 > pm) { pm = e2; am = 2; }
      float p = pm * inv;
      sel[tok] = am;
      pval[tok] = p;
      int s = tok - (tok / 729) * 729;
      atomicAdd(&denom[s * 3 + am], p);
      cloc0 += (am == 0); cloc1 += (am == 1); cloc2 += (am == 2);
    }
  }
  __shared__ int bc[3];
  if (threadIdx.x == 0) { bc[0] = 0; bc[1] = 0; bc[2] = 0; }
  __syncthreads();
  if (lane == 0) {
    if (cloc0) atomicAdd(&bc[0], cloc0);
    if (cloc1) atomicAdd(&bc[1], cloc1);
    if (cloc2) atomicAdd(&bc[2], cloc2);
  }
  __syncthreads();
  if (threadIdx.x < 3 && bc[threadIdx.x]) atomicAdd(&cnt[threadIdx.x], bc[threadIdx.x]);
}

// 128-aligned per-expert offsets
__global__ void moe_scan(const int* __restrict__ cnt, int* __restrict__ poff) {
  int p1 = (cnt[0] + 127) & ~127;
  int p2 = p1 + ((cnt[1] + 127) & ~127);
  int p3 = p2 + ((cnt[2] + 127) & ~127);
  poff[0] = 0; poff[1] = p1; poff[2] = p2; poff[3] = p3;
}

// Block-aggregated scatter: ballot/popcount ranking, 3 atomics per block.
__global__ __launch_bounds__(256) void moe_scatter(const int* __restrict__ sel,
                            const float* __restrict__ pval,
                            const float* __restrict__ denom, const int* __restrict__ poff,
                            int* __restrict__ cur, int* __restrict__ perm,
                            float* __restrict__ gsv) {
  int tok = blockIdx.x * 256 + threadIdx.x;
  int lane = threadIdx.x & 63, w = threadIdx.x >> 6;
  bool valid = tok < N_TOK;
  int e = valid ? sel[tok] : -1;
  if (valid) {
    int s = tok - (tok / 729) * 729;
    gsv[tok] = pval[tok] * 16.f / (denom[s * 3 + e] + 1e-6f);
  }
  unsigned long long m0 = __ballot(e == 0);
  unsigned long long m1 = __ballot(e == 1);
  unsigned long long m2 = __ballot(e == 2);
  __shared__ int wcnt[4][3], wbase[4][3];
  if (lane == 0) {
    wcnt[w][0] = __popcll(m0);
    wcnt[w][1] = __popcll(m1);
    wcnt[w][2] = __popcll(m2);
  }
  __syncthreads();
  if (threadIdx.x < 3) {
    int x = threadIdx.x;
    int c0 = wcnt[0][x], c1 = wcnt[1][x], c2 = wcnt[2][x], c3 = wcnt[3][x];
    int base = atomicAdd(&cur[x], c0 + c1 + c2 + c3);
    wbase[0][x] = base;
    wbase[1][x] = base + c0;
    wbase[2][x] = base + c0 + c1;
    wbase[3][x] = base + c0 + c1 + c2;
  }
  __syncthreads();
  if (valid) {
    unsigned long long lt = (lane == 0) ? 0ull : ((~0ull) >> (64 - lane));
    unsigned long long me = (e == 0) ? m0 : (e == 1) ? m1 : m2;
    int pos = wbase[w][e] + __popcll(me & lt);
    perm[poff[e] + pos] = tok;
  }
}

// ---------------- final: out[b][c][s] = x2 + moe (transposed) ----------------
__global__ void final_k(const float* __restrict__ x2, const float* __restrict__ moe,
                        float* __restrict__ out) {
  __shared__ float L[32][33];
  int b = blockIdx.z, c0 = blockIdx.y * 32, s0 = blockIdx.x * 32;
  int tx = threadIdx.x, ty = threadIdx.y;
#pragma unroll
  for (int i = 0; i < 4; i++) {
    int s = s0 + ty + i * 8;
    float v = 0.f;
    if (s < N_S) {
      size_t tok = (size_t)b * 729 + s;
      v = x2[tok * 768 + c0 + tx] + moe[tok * 768 + c0 + tx];
    }
    L[ty + i * 8][tx] = v;
  }
  __syncthreads();
#pragma unroll
  for (int i = 0; i < 4; i++) {
    int s = s0 + tx;
    int c = c0 + ty + i * 8;
    if (s < N_S) out[((size_t)b * 768 + c) * 729 + s] = L[tx][ty + i * 8];
  }
}

// ---------------- launch ----------------
extern "C" void kernel_launch(void* const* d_in, const int* in_sizes, int n_in,
                              void* d_out, int out_size, void* d_ws, size_t ws_size,
                              hipStream_t stream) {
  (void)in_sizes; (void)n_in; (void)out_size; (void)ws_size;
  const float* x     = (const float*)d_in[0];
  const float* lng   = (const float*)d_in[1];
  const float* lnb   = (const float*)d_in[2];
  const float* wqkv  = (const float*)d_in[3];
  const float* wout  = (const float*)d_in[4];
  const float* wgate = (const float*)d_in[5];
  const float* bgate = (const float*)d_in[6];
  const float* w1    = (const float*)d_in[7];
  const float* b1    = (const float*)d_in[8];
  const float* w2    = (const float*)d_in[9];
  const float* b2    = (const float*)d_in[10];
  float* out = (float*)d_out;
  char* ws = (char*)d_ws;

  bf16* WQKVH = (bf16*)(ws + OFF_WQKVH);
  bf16* WQKVL = (bf16*)(ws + OFF_WQKVL);
  bf16* WOUTH = (bf16*)(ws + OFF_WOUTH);
  bf16* WOUTL = (bf16*)(ws + OFF_WOUTL);
  bf16* W1T   = (bf16*)(ws + OFF_W1T);
  bf16* W2T   = (bf16*)(ws + OFF_W2T);
  float* XTOK = (float*)(ws + OFF_XTOK);
  float* MOE  = (float*)(ws + OFF_XTOK);
  bf16* TOKH  = (bf16*)(ws + OFF_TOKH);
  bf16* TOKL  = (bf16*)(ws + OFF_TOKL);
  bf16* VTH   = (bf16*)(ws + OFF_VTH);
  bf16* VTL   = (bf16*)(ws + OFF_VTL);
  bf16* T2H   = (bf16*)(ws + OFF_T2H);
  bf16* QKH   = (bf16*)(ws + OFF_QKH);
  bf16* QKL   = (bf16*)(ws + OFF_QKL);
  bf16* VPH   = (bf16*)(ws + OFF_VPH);
  bf16* VPL   = (bf16*)(ws + OFF_VPL);
  bf16* CTXH  = (bf16*)(ws + OFF_CTXH);
  bf16* CTXL  = (bf16*)(ws + OFF_CTXL);
  bf16* HMID  = (bf16*)(ws + OFF_HMID);
  float* X2   = (float*)(ws + OFF_X2);
  double* STATS = (double*)(ws + OFF_STATS);
  float* DENOM  = (float*)(ws + OFF_DENOM);
  int*   SEL    = (int*)(ws + OFF_SEL);
  float* PVAL   = (float*)(ws + OFF_PVAL);
  float* GSV    = (float*)(ws + OFF_GSV);
  int*   PERM   = (int*)(ws + OFF_PERM);
  int*   CNT    = (int*)(ws + OFF_CNT);
  int*   POFF   = CNT + 4;
  int*   CUR    = CNT + 8;

  hipMemsetAsync(ws + OFF_STATS, 0, 16384, stream);      // stats + denom
  hipMemsetAsync(ws + OFF_CNT, 0, 64, stream);           // cnt/poff/cur
  hipMemsetAsync(ws + OFF_PERM, 0xFF, MOE_TILES * 128 * 4, stream);  // perm = -1

  dim3 tb(32, 8);
  kxpose<true><<<dim3(72, 24), tb, 0, stream>>>(wqkv, WQKVH, WQKVL, 768, 2304);
  kxpose<true><<<dim3(24, 24), tb, 0, stream>>>(wout, WOUTH, WOUTL, 768, 768);
  for (int e = 0; e < 3; e++) {
    kxpose<false><<<dim3(96, 24), tb, 0, stream>>>(w1 + (size_t)e * 768 * 3072,
        W1T + (size_t)e * 3072 * 768, nullptr, 768, 3072);
    kxpose<false><<<dim3(24, 96), tb, 0, stream>>>(w2 + (size_t)e * 3072 * 768,
        W2T + (size_t)e * 768 * 3072, nullptr, 3072, 768);
  }
  ln_stats<<<2048, 256, 0, stream>>>(x, STATS);
  ln_apply<<<dim3(23, 24, 16), tb, 0, stream>>>(x, lng, lnb, STATS, XTOK, TOKH, TOKL);
  // merged QKV+V projection: one dispatch over all 2304 WQKV columns
  gemm_k<EPI_QKV, true><<<dim3(18, 92), 256, 0, stream>>>(
      TOKH, TOKL, WQKVH, WQKVL, N_TOK, 2304, 768,
      QKH, QKL, VPH, VPL, nullptr, nullptr);
  repack_v<<<dim3(23, 128), 256, 0, stream>>>(VPH, VPL, VTH, VTL);
  attn<<<dim3(12, 128), 256, 0, stream>>>(QKH, QKL, VTH, VTL, CTXH, CTXL);
  gemm_k<EPI_ATTNOUT, true><<<dim3(6, 92), 256, 0, stream>>>(
      CTXH, CTXL, WOUTH, WOUTL, N_TOK, 768, 768,
      T2H, nullptr, nullptr, nullptr, X2, XTOK);
  gate_k<<<GATE_BLOCKS, 256, 0, stream>>>(X2, wgate, bgate, SEL, PVAL, DENOM, CNT);
  moe_scan<<<1, 1, 0, stream>>>(CNT, POFF);
  moe_scatter<<<46, 256, 0, stream>>>(SEL, PVAL, DENOM, POFF, CUR, PERM, GSV);
  gemm_moe1<<<dim3(24, MOE_TILES), 256, 0, stream>>>(T2H, W1T, b1, PERM, POFF, HMID);
  gemm_moe2<<<dim3(6, MOE_TILES), 256, 0, stream>>>(HMID, W2T, b2, PERM, POFF, GSV, MOE);
  final_k<<<dim3(23, 24, 16), tb, 0, stream>>>(X2, MOE, out);
}

// Round 14
// 655.886 us; speedup vs baseline: 1.1080x; 1.1080x over previous
//
#include <hip/hip_runtime.h>

typedef __bf16 bf16;
typedef __bf16 bf16x4_t __attribute__((ext_vector_type(4)));
typedef __bf16 bf16x8_t __attribute__((ext_vector_type(8)));
typedef float f32x4 __attribute__((ext_vector_type(4)));

#define DEVI __device__ __forceinline__

// ---------------- problem constants ----------------
#define N_B   16
#define N_C   768
#define N_S   729
#define N_TOK 11664          // 16*729
#define TOKP  11776          // 92*128 padded token rows
#define N_H   8
#define N_D   96
#define N_HID 3072
#define MOE_TILES 94         // max 128-row tiles after per-expert 128-padding
#define GATE_BLOCKS 183      // 183 blocks * 4 waves * 16 toks = 11712 >= N_TOK

// ---------------- workspace layout (bytes) ----------------
#define OFF_WQKVH 0ull                  // bf16 [2304][768]
#define OFF_WQKVL 3538944ull
#define OFF_WOUTH 7077888ull            // bf16 [768][768]
#define OFF_WOUTL 8257536ull
#define OFF_W1T   9437184ull            // bf16 [3][3072][768]
#define OFF_W2T   23592960ull           // bf16 [3][768][3072]
#define OFF_XTOK  37748736ull           // f32 [TOKP][768]   -> later MOE f32
#define OFF_R3    73924608ull           // TOK hi/lo -> VT hi/lo -> T2H
#define OFF_TOKH  OFF_R3
#define OFF_TOKL  (OFF_R3 + 18087936ull)
#define OFF_VTH   OFF_R3                // bf16 [128][96][736]
#define OFF_VTL   (OFF_R3 + 18087936ull)
#define OFF_T2H   OFF_R3                // bf16 [TOKP][768]
#define OFF_QKH   110100480ull          // bf16 [TOKP][1536] -> HMID (compacted, 12032 rows)
#define OFF_QKL   146276352ull
#define OFF_VPH   182452224ull          // bf16 [TOKP][768]  -> (dead after attn; HMID tail)
#define OFF_VPL   200540160ull
#define OFF_CTXH  OFF_VPH
#define OFF_CTXL  OFF_VPL
#define OFF_HMID  OFF_QKH               // bf16 [12032][3072] = 73.9 MB (QKH..+CTXH head, all dead)
#define OFF_X2    218628096ull          // f32 [TOKP][768]
#define OFF_STATS 254803968ull          // double [16][2]
#define OFF_DENOM (OFF_STATS + 256ull)  // f32 [729][3]
#define OFF_SEL   (OFF_STATS + 16384ull)
#define OFF_PVAL  (OFF_SEL + 65536ull)
#define OFF_GSV   (OFF_PVAL + 65536ull) // f32 [N_TOK]
#define OFF_PERM  (OFF_GSV + 65536ull)  // int [94*128]
#define OFF_CNT   (OFF_PERM + 65536ull) // int cnt[4], poff[4], cur[4]

// ---------------- helpers ----------------
DEVI f32x4 mfma16(bf16x8_t a, bf16x8_t b, f32x4 c) {
  return __builtin_amdgcn_mfma_f32_16x16x32_bf16(a, b, c, 0, 0, 0);
}
// Native RNE conversion (hw cvt; bit-identical to the old RNE bit hack).
DEVI bf16 f2bf(float f) { return (bf16)f; }
DEVI float bf2f(bf16 h) { return (float)h; }
#define GLDS(gp, lp) __builtin_amdgcn_global_load_lds( \
    (__attribute__((address_space(1))) void*)(gp),     \
    (__attribute__((address_space(3))) void*)(lp), 16, 0, 0)

// XCD-aware bijective block remap (T1, m204 uneven-chunk form).
DEVI void xcd_swz(int& bx, int& by) {
  int gx = gridDim.x;
  int nwg = gx * gridDim.y;
  int lin = blockIdx.x + gx * blockIdx.y;
  int xcd = lin & 7, j = lin >> 3;
  int q = nwg >> 3, r = nwg & 7;
  int base = (xcd < r) ? xcd * (q + 1) : r * (q + 1) + (xcd - r) * q;
  int g = base + j;
  by = g / gx;
  bx = g - by * gx;
}

// ---------------- weight transpose + bf16 hi/lo ----------------
template<bool SPLIT>
__global__ void kxpose(const float* __restrict__ in, bf16* __restrict__ oh,
                       bf16* __restrict__ ol, int R, int Cc) {
  __shared__ float T[32][33];
  int c0 = blockIdx.x * 32, r0 = blockIdx.y * 32;
  int tx = threadIdx.x, ty = threadIdx.y;
#pragma unroll
  for (int i = 0; i < 4; i++)
    T[ty + i * 8][tx] = in[(size_t)(r0 + ty + i * 8) * Cc + c0 + tx];
  __syncthreads();
#pragma unroll
  for (int i = 0; i < 4; i++) {
    float v = T[tx][ty + i * 8];
    size_t o = (size_t)(c0 + ty + i * 8) * R + r0 + tx;
    bf16 hh = f2bf(v);
    oh[o] = hh;
    if constexpr (SPLIT) ol[o] = f2bf(v - bf2f(hh));
  }
}

// ---------------- LayerNorm ----------------
__global__ __launch_bounds__(256) void ln_stats(const float* __restrict__ x,
                                                double* __restrict__ stats) {
  int b = blockIdx.x >> 7, ch = blockIdx.x & 127;
  const float* xb = x + (size_t)b * 559872;
  int start = ch * 4374;
  float s = 0.f, ss = 0.f;
  for (int i = start + threadIdx.x; i < start + 4374; i += 256) {
    float v = xb[i];
    s += v; ss += v * v;
  }
#pragma unroll
  for (int o = 32; o > 0; o >>= 1) { s += __shfl_down(s, o); ss += __shfl_down(ss, o); }
  __shared__ float rs[4], rss[4];
  int w = threadIdx.x >> 6;
  if ((threadIdx.x & 63) == 0) { rs[w] = s; rss[w] = ss; }
  __syncthreads();
  if (threadIdx.x == 0) {
    atomicAdd(&stats[b * 2 + 0], (double)(rs[0] + rs[1] + rs[2] + rs[3]));
    atomicAdd(&stats[b * 2 + 1], (double)(rss[0] + rss[1] + rss[2] + rss[3]));
  }
}

__global__ void ln_apply(const float* __restrict__ x, const float* __restrict__ g,
                         const float* __restrict__ be, const double* __restrict__ stats,
                         float* __restrict__ xtok, bf16* __restrict__ th, bf16* __restrict__ tl) {
  __shared__ float TN[32][33], TX[32][33];
  int b = blockIdx.z, c0 = blockIdx.y * 32, s0 = blockIdx.x * 32;
  double mu = stats[b * 2] * (1.0 / 559872.0);
  double var = stats[b * 2 + 1] * (1.0 / 559872.0) - mu * mu;
  float rstd = (float)(1.0 / sqrt(var + 1e-5));
  float muf = (float)mu;
  int tx = threadIdx.x, ty = threadIdx.y;
  size_t bo = (size_t)b * 559872;
#pragma unroll
  for (int i = 0; i < 4; i++) {
    int c = c0 + ty + i * 8, s = s0 + tx;
    float v = 0.f, xn = 0.f;
    if (s < N_S) {
      v = x[bo + (size_t)c * 729 + s];
      xn = (v - muf) * rstd * g[(size_t)c * 729 + s] + be[(size_t)c * 729 + s];
    }
    TX[ty + i * 8][tx] = v;
    TN[ty + i * 8][tx] = xn;
  }
  __syncthreads();
#pragma unroll
  for (int i = 0; i < 4; i++) {
    int s = s0 + ty + i * 8;
    if (s < N_S) {
      size_t tok = (size_t)b * 729 + s;
      int c = c0 + tx;
      float xv = TX[tx][ty + i * 8];
      float xn = TN[tx][ty + i * 8];
      xtok[tok * 768 + c] = xv;
      bf16 hh = f2bf(xn);
      th[tok * 768 + c] = hh;
      tl[tok * 768 + c] = f2bf(xn - bf2f(hh));
    }
  }
}

// ---------------- generic bf16(-split) MFMA GEMM, 128x128 tile, BK=64 ----------------
// R8-proven structure: all four operands staged via global_load_lds (64KB LDS,
// 2 blocks/CU). EPI_QKV: one dispatch over all 2304 WQKV cols.
enum { EPI_QKV = 0, EPI_ATTNOUT = 1 };

template<int EPI, bool SPLIT>
__global__ __launch_bounds__(256, 2)
void gemm_k(const bf16* __restrict__ Ah, const bf16* __restrict__ Al,
            const bf16* __restrict__ Bh, const bf16* __restrict__ Bl,
            int M, int N, int K,
            bf16* __restrict__ o0, bf16* __restrict__ o1,
            bf16* __restrict__ o2, bf16* __restrict__ o3,
            float* __restrict__ of, const float* __restrict__ fa) {
  __shared__ __align__(16) bf16 Ash[8192], Bsh[8192];
  __shared__ __align__(16) bf16 Asl[SPLIT ? 8192 : 8], Bsl[SPLIT ? 8192 : 8];
  const int t = threadIdx.x;
  const int lane = t & 63, w = t >> 6;
  const int wr = (w >> 1) << 6, wc = (w & 1) << 6;
  const int lr = lane & 15, lg = lane >> 4;
  int sbx, sby; xcd_swz(sbx, sby);
  const size_t arow = (size_t)sby * 128;
  const size_t brow = (size_t)sbx * 128;
  const int sr = t >> 3;                        // staging row within 32-row group
  const int sg = ((t & 7) ^ (sr & 7)) << 3;     // pre-swizzled col group (elements)
  const bf16* pA = Ah + (arow + sr) * (size_t)K + sg;
  const bf16* pB = Bh + (brow + sr) * (size_t)K + sg;
  const bf16 *pAl = nullptr, *pBl = nullptr;
  if constexpr (SPLIT) {
    pAl = Al + (arow + sr) * (size_t)K + sg;
    pBl = Bl + (brow + sr) * (size_t)K + sg;
  }
  const size_t rstep = (size_t)K << 5;          // 32 rows
  f32x4 acc[4][4] = {};
  for (int k0 = 0; k0 < K; k0 += 64) {
    __syncthreads();
#pragma unroll
    for (int c = 0; c < 4; c++) {
      GLDS(pA + c * rstep + k0, &Ash[c * 2048 + t * 8]);
      GLDS(pB + c * rstep + k0, &Bsh[c * 2048 + t * 8]);
      if constexpr (SPLIT) {
        GLDS(pAl + c * rstep + k0, &Asl[c * 2048 + t * 8]);
        GLDS(pBl + c * rstep + k0, &Bsl[c * 2048 + t * 8]);
      }
    }
    asm volatile("s_waitcnt vmcnt(0)" ::: "memory");
    __syncthreads();
#pragma unroll
    for (int kk = 0; kk < 2; kk++) {
      bf16x8_t af[4], bq[4], afl[4], bql[4];
#pragma unroll
      for (int m = 0; m < 4; m++) {
        int row = wr + m * 16 + lr;
        int off = row * 64 + ((((kk << 2) | lg) ^ (row & 7)) << 3);
        af[m] = *(const bf16x8_t*)&Ash[off];
        if constexpr (SPLIT) afl[m] = *(const bf16x8_t*)&Asl[off];
      }
#pragma unroll
      for (int n = 0; n < 4; n++) {
        int row = wc + n * 16 + lr;
        int off = row * 64 + ((((kk << 2) | lg) ^ (row & 7)) << 3);
        bq[n] = *(const bf16x8_t*)&Bsh[off];
        if constexpr (SPLIT) bql[n] = *(const bf16x8_t*)&Bsl[off];
      }
#pragma unroll
      for (int m = 0; m < 4; m++)
#pragma unroll
        for (int n = 0; n < 4; n++) {
          acc[m][n] = mfma16(af[m], bq[n], acc[m][n]);
          if constexpr (SPLIT) {
            acc[m][n] = mfma16(af[m], bql[n], acc[m][n]);
            acc[m][n] = mfma16(afl[m], bq[n], acc[m][n]);
          }
        }
    }
  }
#pragma unroll
  for (int m = 0; m < 4; m++) {
#pragma unroll
    for (int r = 0; r < 4; r++) {
      int gr = (int)arow + wr + m * 16 + lg * 4 + r;
      if (gr >= M) continue;
#pragma unroll
      for (int n = 0; n < 4; n++) {
        int gc = (int)brow + wc + n * 16 + lr;
        float v = acc[m][n][r];
        if constexpr (EPI == EPI_QKV) {
          bf16 hh = f2bf(v);
          bf16 ll = f2bf(v - bf2f(hh));
          if (gc < 1536) {
            size_t oidx = (size_t)gr * 1536 + gc;
            o0[oidx] = hh;
            o1[oidx] = ll;
          } else {
            size_t oidx = (size_t)gr * 768 + (gc - 1536);
            o2[oidx] = hh;
            o3[oidx] = ll;
          }
        } else {  // EPI_ATTNOUT
          float x2v = v + fa[(size_t)gr * 768 + gc];
          of[(size_t)gr * 768 + gc] = x2v;
          o0[(size_t)gr * 768 + gc] = f2bf(x2v);
        }
      }
    }
  }
}

// ---------------- grouped MoE GEMM1: gathered A rows, GELU epilogue (BK=64) ----------------
__global__ __launch_bounds__(256, 4)
void gemm_moe1(const bf16* __restrict__ Ah, const bf16* __restrict__ W1T,
               const float* __restrict__ b1, const int* __restrict__ perm,
               const int* __restrict__ poff, bf16* __restrict__ hmid) {
  int sbx, sby; xcd_swz(sbx, sby);
  const int arow = sby * 128;
  if (arow >= poff[3]) return;
  const int e = (arow >= poff[1]) + (arow >= poff[2]);
  const bf16* Bh = W1T + (size_t)e * 3072 * 768;
  const float* bias = b1 + e * 3072;
  __shared__ __align__(16) bf16 Ash[8192], Bsh[8192];
  const int t = threadIdx.x;
  const int lane = t & 63, w = t >> 6;
  const int wr = (w >> 1) << 6, wc = (w & 1) << 6;
  const int lr = lane & 15, lg = lane >> 4;
  const size_t brow = (size_t)sbx * 128;
  const int sr = t >> 3;
  const int sg = ((t & 7) ^ (sr & 7)) << 3;
  int ip[4];
#pragma unroll
  for (int c = 0; c < 4; c++) {
    int ii = perm[arow + c * 32 + sr];
    ip[c] = (ii < 0) ? 0 : ii;
  }
  const bf16* pB = Bh + (brow + sr) * 768 + sg;
  const size_t rstep = 768ull << 5;
  f32x4 acc[4][4] = {};
  for (int k0 = 0; k0 < 768; k0 += 64) {
    __syncthreads();
#pragma unroll
    for (int c = 0; c < 4; c++) {
      GLDS(Ah + (size_t)ip[c] * 768 + sg + k0, &Ash[c * 2048 + t * 8]);
      GLDS(pB + c * rstep + k0, &Bsh[c * 2048 + t * 8]);
    }
    asm volatile("s_waitcnt vmcnt(0)" ::: "memory");
    __syncthreads();
#pragma unroll
    for (int kk = 0; kk < 2; kk++) {
      bf16x8_t af[4], bq[4];
#pragma unroll
      for (int m = 0; m < 4; m++) {
        int row = wr + m * 16 + lr;
        af[m] = *(const bf16x8_t*)&Ash[row * 64 + ((((kk << 2) | lg) ^ (row & 7)) << 3)];
      }
#pragma unroll
      for (int n = 0; n < 4; n++) {
        int row = wc + n * 16 + lr;
        bq[n] = *(const bf16x8_t*)&Bsh[row * 64 + ((((kk << 2) | lg) ^ (row & 7)) << 3)];
      }
#pragma unroll
      for (int m = 0; m < 4; m++)
#pragma unroll
        for (int n = 0; n < 4; n++)
          acc[m][n] = mfma16(af[m], bq[n], acc[m][n]);
    }
  }
#pragma unroll
  for (int m = 0; m < 4; m++)
#pragma unroll
    for (int r = 0; r < 4; r++) {
      int gr = arow + wr + m * 16 + lg * 4 + r;
#pragma unroll
      for (int n = 0; n < 4; n++) {
        int gc = (int)brow + wc + n * 16 + lr;
        float z = acc[m][n][r] + bias[gc];
        float gl = 0.5f * z * (1.f + erff(z * 0.7071067811865476f));
        hmid[(size_t)gr * 3072 + gc] = f2bf(gl);
      }
    }
}

// ---------------- grouped MoE GEMM2: compacted A, scatter epilogue (BK=64) ----------------
__global__ __launch_bounds__(256, 4)
void gemm_moe2(const bf16* __restrict__ hmid, const bf16* __restrict__ W2T,
               const float* __restrict__ b2, const int* __restrict__ perm,
               const int* __restrict__ poff, const float* __restrict__ gsv,
               float* __restrict__ moe) {
  int sbx, sby; xcd_swz(sbx, sby);
  const int arow = sby * 128;
  if (arow >= poff[3]) return;
  const int e = (arow >= poff[1]) + (arow >= poff[2]);
  const bf16* Bh = W2T + (size_t)e * 768 * 3072;
  const float* bias = b2 + e * 768;
  __shared__ __align__(16) bf16 Ash[8192], Bsh[8192];
  const int t = threadIdx.x;
  const int lane = t & 63, w = t >> 6;
  const int wr = (w >> 1) << 6, wc = (w & 1) << 6;
  const int lr = lane & 15, lg = lane >> 4;
  const size_t brow = (size_t)sbx * 128;
  const int sr = t >> 3;
  const int sg = ((t & 7) ^ (sr & 7)) << 3;
  const bf16* pA = hmid + (size_t)(arow + sr) * 3072 + sg;
  const bf16* pB = Bh + (brow + sr) * 3072 + sg;
  const size_t rstep = 3072ull << 5;
  f32x4 acc[4][4] = {};
  for (int k0 = 0; k0 < 3072; k0 += 64) {
    __syncthreads();
#pragma unroll
    for (int c = 0; c < 4; c++) {
      GLDS(pA + c * rstep + k0, &Ash[c * 2048 + t * 8]);
      GLDS(pB + c * rstep + k0, &Bsh[c * 2048 + t * 8]);
    }
    asm volatile("s_waitcnt vmcnt(0)" ::: "memory");
    __syncthreads();
#pragma unroll
    for (int kk = 0; kk < 2; kk++) {
      bf16x8_t af[4], bq[4];
#pragma unroll
      for (int m = 0; m < 4; m++) {
        int row = wr + m * 16 + lr;
        af[m] = *(const bf16x8_t*)&Ash[row * 64 + ((((kk << 2) | lg) ^ (row & 7)) << 3)];
      }
#pragma unroll
      for (int n = 0; n < 4; n++) {
        int row = wc + n * 16 + lr;
        bq[n] = *(const bf16x8_t*)&Bsh[row * 64 + ((((kk << 2) | lg) ^ (row & 7)) << 3)];
      }
#pragma unroll
      for (int m = 0; m < 4; m++)
#pragma unroll
        for (int n = 0; n < 4; n++)
          acc[m][n] = mfma16(af[m], bq[n], acc[m][n]);
    }
  }
#pragma unroll
  for (int m = 0; m < 4; m++)
#pragma unroll
    for (int r = 0; r < 4; r++) {
      int gr = arow + wr + m * 16 + lg * 4 + r;
      int tok = perm[gr];
      if (tok < 0) continue;
      float gv = gsv[tok];
#pragma unroll
      for (int n = 0; n < 4; n++) {
        int gc = (int)brow + wc + n * 16 + lr;
        moe[(size_t)tok * 768 + gc] = (acc[m][n][r] + bias[gc]) * gv;
      }
    }
}

// ---------------- V repack: [tok][h*96+d] -> [bh][96][736] (zero pad s>=729) ----------------
__global__ __launch_bounds__(256) void repack_v(const bf16* __restrict__ vph,
    const bf16* __restrict__ vpl, bf16* __restrict__ vth, bf16* __restrict__ vtl) {
  __shared__ bf16 Lh[96][40], Ll[96][40];
  int t = threadIdx.x;
  int bh = blockIdx.y, b = bh >> 3, h = bh & 7;
  int s0 = blockIdx.x * 32;
  for (int v = t; v < 384; v += 256) {
    int e0 = v * 8;
    int r = e0 / 96;
    int c = e0 - r * 96;
    size_t src = ((size_t)b * 729 + s0 + r) * 768 + h * 96 + c;
    bf16x8_t xh = *(const bf16x8_t*)&vph[src];
    bf16x8_t xl = *(const bf16x8_t*)&vpl[src];
    bool ok = (s0 + r) < N_S;
#pragma unroll
    for (int j = 0; j < 8; j++) {
      Lh[c + j][r] = ok ? xh[j] : f2bf(0.f);
      Ll[c + j][r] = ok ? xl[j] : f2bf(0.f);
    }
  }
  __syncthreads();
  for (int vv = t; vv < 768; vv += 256) {
    int e0 = vv * 4;
    int d = e0 >> 5, sl = e0 & 31;
    bf16x4_t ohv, olv;
#pragma unroll
    for (int j = 0; j < 4; j++) { ohv[j] = Lh[d][sl + j]; olv[j] = Ll[d][sl + j]; }
    size_t dst = (size_t)bh * (96ull * 736ull) + (size_t)d * 736 + s0 + sl;
    *(bf16x4_t*)&vth[dst] = ohv;
    *(bf16x4_t*)&vtl[dst] = olv;
  }
}

// ---------------- fused attention (split bf16, online softmax) ----------------
// Proven R6 structure (256 thr, QBLK=64, LDS 48KB, 3 blocks/CU, 84 VGPR).
DEVI int pslot(int w, int s) { return ((s >> 9) << 11) + (w << 9) + (s & 511); }

__global__ __launch_bounds__(256, 3)
void attn(const bf16* __restrict__ qkh, const bf16* __restrict__ qkl,
          const bf16* __restrict__ vth, const bf16* __restrict__ vtl,
          bf16* __restrict__ ch, bf16* __restrict__ cl) {
  __shared__ bf16 Ksh[6144], Ksl[6144], Vsh[6144], Vsl[6144];
  const int t = threadIdx.x, lane = t & 63, w = t >> 6;
  const int lr = lane & 15, lg = lane >> 4;
  int sbx, sby; xcd_swz(sbx, sby);
  const int bh = sby, b = bh >> 3, h = bh & 7;
  const int q0 = sbx * 64;
  const size_t tokbase = (size_t)b * 729;
  const int qr = w * 16 + lr;
  const size_t qrow = (tokbase + q0 + qr) * 1536ull + (size_t)h * 96;
  bf16x8_t qh[3], ql[3];
#pragma unroll
  for (int ks = 0; ks < 3; ks++) {
    qh[ks] = *(const bf16x8_t*)&qkh[qrow + ks * 32 + lg * 8];
    ql[ks] = *(const bf16x8_t*)&qkl[qrow + ks * 32 + lg * 8];
  }

  auto loadK = [&](int kt) {
    const int kv0 = kt * 64;
#pragma unroll
    for (int chk = 0; chk < 3; chk++) {
      int kv = t >> 2, dg = t & 3;
      int sdg = dg ^ (kv & 3);
      size_t ksrc = (tokbase + kv0 + kv) * 1536ull + 768ull + (size_t)h * 96 + chk * 32 + (sdg << 3);
      int ldsoff = chk * 2048 + t * 8;
      GLDS(qkh + ksrc, &Ksh[ldsoff]);
      GLDS(qkl + ksrc, &Ksl[ldsoff]);
    }
  };
  auto loadV = [&](int kt) {
    const int kv0 = kt * 64;
#pragma unroll
    for (int chk = 0; chk < 3; chk++) {
      int ldsoff = chk * 2048 + t * 8;
      int d = ldsoff >> 6;
      int grp = (ldsoff >> 3) & 7;
      int sg = grp ^ (d & 7);
      size_t vsrc = (size_t)bh * (96ull * 736ull) + (size_t)d * 736 + kv0 + (sg << 3);
      GLDS(vth + vsrc, &Vsh[ldsoff]);
      GLDS(vtl + vsrc, &Vsl[ldsoff]);
    }
  };

  float mrow[4] = {-1e30f, -1e30f, -1e30f, -1e30f};
  float lpart[4] = {0.f, 0.f, 0.f, 0.f};   // per-lane partial denominators
  f32x4 octx[6] = {};

  // prologue: K[0] fully staged (Q loads drained together), then launch V[0]
  loadK(0);
  asm volatile("s_waitcnt vmcnt(0)" ::: "memory");
  __syncthreads();
  loadV(0);

  for (int kt = 0; kt < 12; kt++) {
    const int kv0 = kt * 64;
    // ---- QK^T from Ksh (V[kt] loads in flight underneath) ----
    f32x4 sc[4];
    __builtin_amdgcn_s_setprio(1);
#pragma unroll
    for (int cf = 0; cf < 4; cf++) {
      f32x4 a = {0.f, 0.f, 0.f, 0.f};
      int kvrow = cf * 16 + lr;
#pragma unroll
      for (int ks = 0; ks < 3; ks++) {
        int slot = ks * 2048 + kvrow * 32 + ((lg ^ (kvrow & 3)) << 3);
        bf16x8_t kh = *(const bf16x8_t*)&Ksh[slot];
        bf16x8_t kl = *(const bf16x8_t*)&Ksl[slot];
        a = mfma16(qh[ks], kh, a);
        a = mfma16(qh[ks], kl, a);
        a = mfma16(ql[ks], kh, a);
      }
      if (kv0 + kvrow >= N_S) { a[0] = -1e30f; a[1] = -1e30f; a[2] = -1e30f; a[3] = -1e30f; }
      sc[cf] = a;
    }
    __builtin_amdgcn_s_setprio(0);
    // ---- online softmax with defer-max (THR=8) ----
    float lmax[4];
#pragma unroll
    for (int r = 0; r < 4; r++)
      lmax[r] = fmaxf(fmaxf(sc[0][r], sc[1][r]), fmaxf(sc[2][r], sc[3][r]));
    bool ok = (lmax[0] <= mrow[0] + 8.f) && (lmax[1] <= mrow[1] + 8.f) &&
              (lmax[2] <= mrow[2] + 8.f) && (lmax[3] <= mrow[3] + 8.f);
    if (!__all(ok)) {
      float escv[4];
#pragma unroll
      for (int r = 0; r < 4; r++) {
        float a = lmax[r];
#pragma unroll
        for (int o = 1; o < 16; o <<= 1) a = fmaxf(a, __shfl_xor(a, o));
        float mn = fmaxf(mrow[r], a);
        escv[r] = __expf(mrow[r] - mn);
        mrow[r] = mn;
        lpart[r] *= escv[r];
      }
#pragma unroll
      for (int df = 0; df < 6; df++)
#pragma unroll
        for (int r = 0; r < 4; r++) octx[df][r] *= escv[r];
    }
#pragma unroll
    for (int cf = 0; cf < 4; cf++)
#pragma unroll
      for (int r = 0; r < 4; r++) {
        float p = __expf(sc[cf][r] - mrow[r]);
        sc[cf][r] = p;
        lpart[r] += p;
      }
    // drain own V[kt]; barrier => everyone done reading Ksh, V tile complete
    asm volatile("s_waitcnt vmcnt(0)" ::: "memory");
    __syncthreads();
    // ---- P into own slice of dead K tile (wave-private) ----
#pragma unroll
    for (int cf = 0; cf < 4; cf++)
#pragma unroll
      for (int r = 0; r < 4; r++) {
        int qloc = lg * 4 + r;
        int kvg = (cf << 1) | (lr >> 3);
        int xw = (qloc ^ (qloc >> 2)) & 7;
        int slot = qloc * 64 + (((kvg ^ xw) << 3) | (lr & 7));
        float p = sc[cf][r];
        bf16 hp = f2bf(p);
        int ps = pslot(w, slot);
        Ksh[ps] = hp;
        Ksl[ps] = f2bf(p - bf2f(hp));
      }
    asm volatile("s_waitcnt lgkmcnt(0)" ::: "memory");
    __builtin_amdgcn_sched_barrier(0);
    bf16x8_t pah[2], pal[2];
#pragma unroll
    for (int ks = 0; ks < 2; ks++) {
      int xr = (lr ^ (lr >> 2)) & 7;
      int slot = lr * 64 + ((((ks << 2) | lg) ^ xr) << 3);
      int ps = pslot(w, slot);
      pah[ks] = *(const bf16x8_t*)&Ksh[ps];
      pal[ks] = *(const bf16x8_t*)&Ksl[ps];
    }
    asm volatile("s_waitcnt lgkmcnt(0)" ::: "memory");
    __builtin_amdgcn_sched_barrier(0);
    // P fragments now in registers: safe to launch K[kt+1] over own K/P slice
    if (kt < 11) loadK(kt + 1);
    // ---- PV from Vsh (K[kt+1] loads in flight underneath) ----
    __builtin_amdgcn_s_setprio(1);
#pragma unroll
    for (int df = 0; df < 6; df++) {
      int dd = df * 16 + lr;
#pragma unroll
      for (int ks = 0; ks < 2; ks++) {
        int slot = dd * 64 + ((((ks << 2) | lg) ^ (dd & 7)) << 3);
        bf16x8_t vh = *(const bf16x8_t*)&Vsh[slot];
        bf16x8_t vl = *(const bf16x8_t*)&Vsl[slot];
        octx[df] = mfma16(pah[ks], vh, octx[df]);
        octx[df] = mfma16(pah[ks], vl, octx[df]);
        octx[df] = mfma16(pal[ks], vh, octx[df]);
      }
    }
    __builtin_amdgcn_s_setprio(0);
    if (kt < 11) {
      // drain own K[kt+1]; barrier => everyone done reading Vsh, K complete
      asm volatile("s_waitcnt vmcnt(0)" ::: "memory");
      __syncthreads();
      loadV(kt + 1);
    }
  }
  // epilogue: reduce per-lane partial denominators across the 16-lane row group
  float lrow[4];
#pragma unroll
  for (int r = 0; r < 4; r++) {
    float a = lpart[r];
#pragma unroll
    for (int o = 1; o < 16; o <<= 1) a += __shfl_xor(a, o);
    lrow[r] = a;
  }
#pragma unroll
  for (int r = 0; r < 4; r++) {
    int qloc = w * 16 + lg * 4 + r;
    if (q0 + qloc >= N_S) continue;
    size_t orow = (tokbase + q0 + qloc) * 768ull + (size_t)h * 96;
    float inv = 1.f / lrow[r];
#pragma unroll
    for (int df = 0; df < 6; df++) {
      float v = octx[df][r] * inv;
      bf16 hh = f2bf(v);
      ch[orow + df * 16 + lr] = hh;
      cl[orow + df * 16 + lr] = f2bf(v - bf2f(hh));
    }
  }
}

// ---------------- gate: fp64 logits, argmax, cross-batch denom, counts ----------------
__global__ __launch_bounds__(256) void gate_k(const float* __restrict__ x2,
    const float* __restrict__ wg, const float* __restrict__ bg,
    int* __restrict__ sel, float* __restrict__ pval, float* __restrict__ denom,
    int* __restrict__ cnt) {
  int lane = threadIdx.x & 63, w = threadIdx.x >> 6;
  float wv[12][3];
#pragma unroll
  for (int j = 0; j < 12; j++) {
    int c = lane + j * 64;
    const float* wgc = wg + c * 3;
    wv[j][0] = wgc[0]; wv[j][1] = wgc[1]; wv[j][2] = wgc[2];
  }
  float bg0 = bg[0], bg1 = bg[1], bg2 = bg[2];
  int cloc0 = 0, cloc1 = 0, cloc2 = 0;
  int base_tok = (blockIdx.x * 4 + w) * 16;
  for (int it = 0; it < 16; it++) {
    int tok = base_tok + it;
    if (tok >= N_TOK) break;   // wave-uniform
    const float* row = x2 + (size_t)tok * 768;
    double a0 = 0, a1 = 0, a2 = 0;
#pragma unroll
    for (int j = 0; j < 12; j++) {
      float xv = row[lane + j * 64];
      a0 += (double)(xv * wv[j][0]);
      a1 += (double)(xv * wv[j][1]);
      a2 += (double)(xv * wv[j][2]);
    }
#pragma unroll
    for (int o = 32; o > 0; o >>= 1) {
      a0 += __shfl_down(a0, o);
      a1 += __shfl_down(a1, o);
      a2 += __shfl_down(a2, o);
    }
    if (lane == 0) {
      float g0 = (float)a0 + bg0, g1 = (float)a1 + bg1, g2 = (float)a2 + bg2;
      float mx = fmaxf(g0, fmaxf(g1, g2));
      float e0 = __expf(g0 - mx), e1 = __expf(g1 - mx), e2 = __expf(g2 - mx);
      float inv = 1.f / (e0 + e1 + e2);
      int am = 0; float pm = e0;
      if (e1 > pm) { pm = e1; am = 1; }
      if (e2 > pm) { pm = e2; am = 2; }
      float p = pm * inv;
      sel[tok] = am;
      pval[tok] = p;
      int s = tok - (tok / 729) * 729;
      atomicAdd(&denom[s * 3 + am], p);
      cloc0 += (am == 0); cloc1 += (am == 1); cloc2 += (am == 2);
    }
  }
  __shared__ int bc[3];
  if (threadIdx.x == 0) { bc[0] = 0; bc[1] = 0; bc[2] = 0; }
  __syncthreads();
  if (lane == 0) {
    if (cloc0) atomicAdd(&bc[0], cloc0);
    if (cloc1) atomicAdd(&bc[1], cloc1);
    if (cloc2) atomicAdd(&bc[2], cloc2);
  }
  __syncthreads();
  if (threadIdx.x < 3 && bc[threadIdx.x]) atomicAdd(&cnt[threadIdx.x], bc[threadIdx.x]);
}

// 128-aligned per-expert offsets
__global__ void moe_scan(const int* __restrict__ cnt, int* __restrict__ poff) {
  int p1 = (cnt[0] + 127) & ~127;
  int p2 = p1 + ((cnt[1] + 127) & ~127);
  int p3 = p2 + ((cnt[2] + 127) & ~127);
  poff[0] = 0; poff[1] = p1; poff[2] = p2; poff[3] = p3;
}

// Block-aggregated scatter: ballot/popcount ranking, 3 atomics per block.
__global__ __launch_bounds__(256) void moe_scatter(const int* __restrict__ sel,
                            const float* __restrict__ pval,
                            const float* __restrict__ denom, const int* __restrict__ poff,
                            int* __restrict__ cur, int* __restrict__ perm,
                            float* __restrict__ gsv) {
  int tok = blockIdx.x * 256 + threadIdx.x;
  int lane = threadIdx.x & 63, w = threadIdx.x >> 6;
  bool valid = tok < N_TOK;
  int e = valid ? sel[tok] : -1;
  if (valid) {
    int s = tok - (tok / 729) * 729;
    gsv[tok] = pval[tok] * 16.f / (denom[s * 3 + e] + 1e-6f);
  }
  unsigned long long m0 = __ballot(e == 0);
  unsigned long long m1 = __ballot(e == 1);
  unsigned long long m2 = __ballot(e == 2);
  __shared__ int wcnt[4][3], wbase[4][3];
  if (lane == 0) {
    wcnt[w][0] = __popcll(m0);
    wcnt[w][1] = __popcll(m1);
    wcnt[w][2] = __popcll(m2);
  }
  __syncthreads();
  if (threadIdx.x < 3) {
    int x = threadIdx.x;
    int c0 = wcnt[0][x], c1 = wcnt[1][x], c2 = wcnt[2][x], c3 = wcnt[3][x];
    int base = atomicAdd(&cur[x], c0 + c1 + c2 + c3);
    wbase[0][x] = base;
    wbase[1][x] = base + c0;
    wbase[2][x] = base + c0 + c1;
    wbase[3][x] = base + c0 + c1 + c2;
  }
  __syncthreads();
  if (valid) {
    unsigned long long lt = (lane == 0) ? 0ull : ((~0ull) >> (64 - lane));
    unsigned long long me = (e == 0) ? m0 : (e == 1) ? m1 : m2;
    int pos = wbase[w][e] + __popcll(me & lt);
    perm[poff[e] + pos] = tok;
  }
}

// ---------------- final: out[b][c][s] = x2 + moe (transposed) ----------------
__global__ void final_k(const float* __restrict__ x2, const float* __restrict__ moe,
                        float* __restrict__ out) {
  __shared__ float L[32][33];
  int b = blockIdx.z, c0 = blockIdx.y * 32, s0 = blockIdx.x * 32;
  int tx = threadIdx.x, ty = threadIdx.y;
#pragma unroll
  for (int i = 0; i < 4; i++) {
    int s = s0 + ty + i * 8;
    float v = 0.f;
    if (s < N_S) {
      size_t tok = (size_t)b * 729 + s;
      v = x2[tok * 768 + c0 + tx] + moe[tok * 768 + c0 + tx];
    }
    L[ty + i * 8][tx] = v;
  }
  __syncthreads();
#pragma unroll
  for (int i = 0; i < 4; i++) {
    int s = s0 + tx;
    int c = c0 + ty + i * 8;
    if (s < N_S) out[((size_t)b * 768 + c) * 729 + s] = L[tx][ty + i * 8];
  }
}

// ---------------- launch ----------------
extern "C" void kernel_launch(void* const* d_in, const int* in_sizes, int n_in,
                              void* d_out, int out_size, void* d_ws, size_t ws_size,
                              hipStream_t stream) {
  (void)in_sizes; (void)n_in; (void)out_size; (void)ws_size;
  const float* x     = (const float*)d_in[0];
  const float* lng   = (const float*)d_in[1];
  const float* lnb   = (const float*)d_in[2];
  const float* wqkv  = (const float*)d_in[3];
  const float* wout  = (const float*)d_in[4];
  const float* wgate = (const float*)d_in[5];
  const float* bgate = (const float*)d_in[6];
  const float* w1    = (const float*)d_in[7];
  const float* b1    = (const float*)d_in[8];
  const float* w2    = (const float*)d_in[9];
  const float* b2    = (const float*)d_in[10];
  float* out = (float*)d_out;
  char* ws = (char*)d_ws;

  bf16* WQKVH = (bf16*)(ws + OFF_WQKVH);
  bf16* WQKVL = (bf16*)(ws + OFF_WQKVL);
  bf16* WOUTH = (bf16*)(ws + OFF_WOUTH);
  bf16* WOUTL = (bf16*)(ws + OFF_WOUTL);
  bf16* W1T   = (bf16*)(ws + OFF_W1T);
  bf16* W2T   = (bf16*)(ws + OFF_W2T);
  float* XTOK = (float*)(ws + OFF_XTOK);
  float* MOE  = (float*)(ws + OFF_XTOK);
  bf16* TOKH  = (bf16*)(ws + OFF_TOKH);
  bf16* TOKL  = (bf16*)(ws + OFF_TOKL);
  bf16* VTH   = (bf16*)(ws + OFF_VTH);
  bf16* VTL   = (bf16*)(ws + OFF_VTL);
  bf16* T2H   = (bf16*)(ws + OFF_T2H);
  bf16* QKH   = (bf16*)(ws + OFF_QKH);
  bf16* QKL   = (bf16*)(ws + OFF_QKL);
  bf16* VPH   = (bf16*)(ws + OFF_VPH);
  bf16* VPL   = (bf16*)(ws + OFF_VPL);
  bf16* CTXH  = (bf16*)(ws + OFF_CTXH);
  bf16* CTXL  = (bf16*)(ws + OFF_CTXL);
  bf16* HMID  = (bf16*)(ws + OFF_HMID);
  float* X2   = (float*)(ws + OFF_X2);
  double* STATS = (double*)(ws + OFF_STATS);
  float* DENOM  = (float*)(ws + OFF_DENOM);
  int*   SEL    = (int*)(ws + OFF_SEL);
  float* PVAL   = (float*)(ws + OFF_PVAL);
  float* GSV    = (float*)(ws + OFF_GSV);
  int*   PERM   = (int*)(ws + OFF_PERM);
  int*   CNT    = (int*)(ws + OFF_CNT);
  int*   POFF   = CNT + 4;
  int*   CUR    = CNT + 8;

  hipMemsetAsync(ws + OFF_STATS, 0, 16384, stream);      // stats + denom
  hipMemsetAsync(ws + OFF_CNT, 0, 64, stream);           // cnt/poff/cur
  hipMemsetAsync(ws + OFF_PERM, 0xFF, MOE_TILES * 128 * 4, stream);  // perm = -1

  dim3 tb(32, 8);
  kxpose<true><<<dim3(72, 24), tb, 0, stream>>>(wqkv, WQKVH, WQKVL, 768, 2304);
  kxpose<true><<<dim3(24, 24), tb, 0, stream>>>(wout, WOUTH, WOUTL, 768, 768);
  for (int e = 0; e < 3; e++) {
    kxpose<false><<<dim3(96, 24), tb, 0, stream>>>(w1 + (size_t)e * 768 * 3072,
        W1T + (size_t)e * 3072 * 768, nullptr, 768, 3072);
    kxpose<false><<<dim3(24, 96), tb, 0, stream>>>(w2 + (size_t)e * 3072 * 768,
        W2T + (size_t)e * 768 * 3072, nullptr, 3072, 768);
  }
  ln_stats<<<2048, 256, 0, stream>>>(x, STATS);
  ln_apply<<<dim3(23, 24, 16), tb, 0, stream>>>(x, lng, lnb, STATS, XTOK, TOKH, TOKL);
  // merged QKV+V projection: one dispatch over all 2304 WQKV columns
  gemm_k<EPI_QKV, true><<<dim3(18, 92), 256, 0, stream>>>(
      TOKH, TOKL, WQKVH, WQKVL, N_TOK, 2304, 768,
      QKH, QKL, VPH, VPL, nullptr, nullptr);
  repack_v<<<dim3(23, 128), 256, 0, stream>>>(VPH, VPL, VTH, VTL);
  attn<<<dim3(12, 128), 256, 0, stream>>>(QKH, QKL, VTH, VTL, CTXH, CTXL);
  gemm_k<EPI_ATTNOUT, true><<<dim3(6, 92), 256, 0, stream>>>(
      CTXH, CTXL, WOUTH, WOUTL, N_TOK, 768, 768,
      T2H, nullptr, nullptr, nullptr, X2, XTOK);
  gate_k<<<GATE_BLOCKS, 256, 0, stream>>>(X2, wgate, bgate, SEL, PVAL, DENOM, CNT);
  moe_scan<<<1, 1, 0, stream>>>(CNT, POFF);
  moe_scatter<<<46, 256, 0, stream>>>(SEL, PVAL, DENOM, POFF, CUR, PERM, GSV);
  gemm_moe1<<<dim3(24, MOE_TILES), 256, 0, stream>>>(T2H, W1T, b1, PERM, POFF, HMID);
  gemm_moe2<<<dim3(6, MOE_TILES), 256, 0, stream>>>(HMID, W2T, b2, PERM, POFF, GSV, MOE);
  final_k<<<dim3(23, 24, 16), tb, 0, stream>>>(X2, MOE, out);
}